// Round 1
// baseline (502.013 us; speedup 1.0000x reference)
//
#include <hip/hip_runtime.h>
#include <cstddef>

#define B_ 8
#define H_ 1024
#define W_ 1024
#define NW_ 5
#define CHUNKS_ 8
#define CHROWS_ (H_ / CHUNKS_)   // 128

// ---------------------------------------------------------------------------
// K1: per-row inclusive prefix sums of centered values:
//   P1 = prefix(x - 0.5), P2 = prefix(x^2 - 1/3)
// Centering keeps SAT magnitudes ~1e3 (random walk) instead of ~5e5, so f32
// corner differences stay accurate to ~1e-4 in the means.
// One block per (y, b) row; 256 threads x float4 = 1024 elements.
// ---------------------------------------------------------------------------
__global__ __launch_bounds__(256) void k_rowscan(const float* __restrict__ x,
                                                 float* __restrict__ P1,
                                                 float* __restrict__ P2) {
  const int y = blockIdx.x, b = blockIdx.y, tid = threadIdx.x;
  const size_t rowoff = ((size_t)b * H_ + y) * W_;
  const float4 v = reinterpret_cast<const float4*>(x + rowoff)[tid];

  float c1[4], c2[4];
  c1[0] = v.x - 0.5f; c1[1] = v.y - 0.5f; c1[2] = v.z - 0.5f; c1[3] = v.w - 0.5f;
  c2[0] = v.x * v.x - (1.0f / 3.0f);
  c2[1] = v.y * v.y - (1.0f / 3.0f);
  c2[2] = v.z * v.z - (1.0f / 3.0f);
  c2[3] = v.w * v.w - (1.0f / 3.0f);

  // local inclusive prefixes
  float i1[4], i2[4];
  i1[0] = c1[0]; i2[0] = c2[0];
  #pragma unroll
  for (int j = 1; j < 4; ++j) { i1[j] = i1[j - 1] + c1[j]; i2[j] = i2[j - 1] + c2[j]; }
  const float s1 = i1[3], s2 = i2[3];

  // block-wide inclusive scan of per-thread sums (Hillis-Steele, in place)
  __shared__ float sh1[256], sh2[256];
  sh1[tid] = s1; sh2[tid] = s2;
  __syncthreads();
  #pragma unroll
  for (int off = 1; off < 256; off <<= 1) {
    float t1 = 0.f, t2 = 0.f;
    if (tid >= off) { t1 = sh1[tid - off]; t2 = sh2[tid - off]; }
    __syncthreads();
    sh1[tid] += t1; sh2[tid] += t2;
    __syncthreads();
  }
  const float e1 = sh1[tid] - s1;  // exclusive prefix of thread sums
  const float e2 = sh2[tid] - s2;

  float4 o1, o2;
  o1.x = e1 + i1[0]; o1.y = e1 + i1[1]; o1.z = e1 + i1[2]; o1.w = e1 + i1[3];
  o2.x = e2 + i2[0]; o2.y = e2 + i2[1]; o2.z = e2 + i2[2]; o2.w = e2 + i2[3];
  reinterpret_cast<float4*>(P1 + rowoff)[tid] = o1;
  reinterpret_cast<float4*>(P2 + rowoff)[tid] = o2;
}

// ---------------------------------------------------------------------------
// K2a: per-(batch, chunk, column) sums over CHROWS_ rows of P1/P2
// grid (W/256, CHUNKS_, B), block 256. Coalesced column walk.
// ---------------------------------------------------------------------------
__global__ __launch_bounds__(256) void k_colpart(const float* __restrict__ P1,
                                                 const float* __restrict__ P2,
                                                 float* __restrict__ part1,
                                                 float* __restrict__ part2) {
  const int x = blockIdx.x * 256 + threadIdx.x;
  const int ch = blockIdx.y, b = blockIdx.z;
  const float* p1 = P1 + ((size_t)b * H_ + (size_t)ch * CHROWS_) * W_ + x;
  const float* p2 = P2 + ((size_t)b * H_ + (size_t)ch * CHROWS_) * W_ + x;
  float s1 = 0.f, s2 = 0.f;
  #pragma unroll 8
  for (int i = 0; i < CHROWS_; ++i) {
    s1 += p1[(size_t)i * W_];
    s2 += p2[(size_t)i * W_];
  }
  const size_t o = ((size_t)(b * CHUNKS_ + ch)) * W_ + x;
  part1[o] = s1; part2[o] = s2;
}

// ---------------------------------------------------------------------------
// K2b: in-place exclusive scan of the CHUNKS_ chunk sums per (b, x)
// ---------------------------------------------------------------------------
__global__ __launch_bounds__(256) void k_chunkscan(float* __restrict__ part1,
                                                   float* __restrict__ part2) {
  const int idx = blockIdx.x * 256 + threadIdx.x;  // b*W_ + x, total B_*W_
  const int b = idx / W_, x = idx - b * W_;
  float r1 = 0.f, r2 = 0.f;
  #pragma unroll
  for (int ch = 0; ch < CHUNKS_; ++ch) {
    const size_t o = ((size_t)(b * CHUNKS_ + ch)) * W_ + x;
    const float v1 = part1[o], v2 = part2[o];
    part1[o] = r1; part2[o] = r2;
    r1 += v1; r2 += v2;
  }
}

// ---------------------------------------------------------------------------
// K2c: finish the column scan in place: P becomes the full 2-D SAT.
// ---------------------------------------------------------------------------
__global__ __launch_bounds__(256) void k_colscan(float* __restrict__ P1,
                                                 float* __restrict__ P2,
                                                 const float* __restrict__ part1,
                                                 const float* __restrict__ part2) {
  const int x = blockIdx.x * 256 + threadIdx.x;
  const int ch = blockIdx.y, b = blockIdx.z;
  const size_t po = ((size_t)(b * CHUNKS_ + ch)) * W_ + x;
  float r1 = part1[po], r2 = part2[po];
  float* p1 = P1 + ((size_t)b * H_ + (size_t)ch * CHROWS_) * W_ + x;
  float* p2 = P2 + ((size_t)b * H_ + (size_t)ch * CHROWS_) * W_ + x;
  #pragma unroll 4
  for (int i = 0; i < CHROWS_; ++i) {
    const size_t o = (size_t)i * W_;
    r1 += p1[o]; p1[o] = r1;
    r2 += p2[o]; p2[o] = r2;
  }
}

// ---------------------------------------------------------------------------
// K3: corner lookups + Sauvola. One block per (y, b) row; 4 px/thread,
// all 5 windows per thread. Counts are analytic (rows_in * cols_in), which
// equals the reference's count-SAT exactly. Clamped corners == zero padding.
// ---------------------------------------------------------------------------
__global__ __launch_bounds__(256) void k_out(const float* __restrict__ S1,
                                             const float* __restrict__ S2,
                                             const float* __restrict__ kk,
                                             const float* __restrict__ RR,
                                             float* __restrict__ out) {
  const int y = blockIdx.x, b = blockIdx.y, tid = threadIdx.x;
  const int x0 = tid * 4;
  const float* base1 = S1 + (size_t)b * H_ * W_;
  const float* base2 = S2 + (size_t)b * H_ * W_;
  const int rad[NW_] = {3, 7, 15, 31, 63};

  float T[NW_][4];
  #pragma unroll
  for (int iw = 0; iw < NW_; ++iw) {
    const int r = rad[iw];
    const float kw = kk[iw];
    const float invR = __builtin_amdgcn_rcpf(RR[iw]);
    const int yB = min(y + r, H_ - 1);
    const int yT = y - r - 1;
    const bool hasT = (yT >= 0);
    const float rows = (float)(yB - max(y - r, 0) + 1);
    const float* rB1 = base1 + (size_t)yB * W_;
    const float* rB2 = base2 + (size_t)yB * W_;
    const float* rT1 = base1 + (size_t)max(yT, 0) * W_;
    const float* rT2 = base2 + (size_t)max(yT, 0) * W_;
    #pragma unroll
    for (int j = 0; j < 4; ++j) {
      const int xx = x0 + j;
      const int xR = min(xx + r, W_ - 1);
      const int xL = xx - r - 1;
      const bool hasL = (xL >= 0);
      float s1 = rB1[xR];
      float s2 = rB2[xR];
      if (hasT) { s1 -= rT1[xR]; s2 -= rT2[xR]; }
      if (hasL) {
        s1 -= rB1[xL]; s2 -= rB2[xL];
        if (hasT) { s1 += rT1[xL]; s2 += rT2[xL]; }
      }
      const float cols = (float)(xR - max(xx - r, 0) + 1);
      const float inv = __builtin_amdgcn_rcpf(rows * cols);
      const float Ex  = s1 * inv + 0.5f;
      const float Ex2 = s2 * inv + (1.0f / 3.0f);
      const float var = Ex2 - Ex * Ex;
      const float dev = __builtin_amdgcn_sqrtf(fmaxf(var, 1e-6f));
      T[iw][j] = Ex * (1.0f + kw * (dev * invR - 1.0f));
    }
  }

  #pragma unroll
  for (int iw = 0; iw < NW_; ++iw) {
    float4 o;
    o.x = T[iw][0]; o.y = T[iw][1]; o.z = T[iw][2]; o.w = T[iw][3];
    reinterpret_cast<float4*>(out + (((size_t)b * NW_ + iw) * H_ + y) * W_)[tid] = o;
  }
}

// ---------------------------------------------------------------------------
extern "C" void kernel_launch(void* const* d_in, const int* in_sizes, int n_in,
                              void* d_out, int out_size, void* d_ws, size_t ws_size,
                              hipStream_t stream) {
  const float* x  = (const float*)d_in[0];
  const float* kk = (const float*)d_in[1];
  const float* RR = (const float*)d_in[2];
  float* out = (float*)d_out;

  const size_t plane = (size_t)B_ * H_ * W_;      // 8M floats = 32 MB
  float* P1 = (float*)d_ws;
  float* P2 = P1 + plane;
  float* part1 = P2 + plane;                      // B*CHUNKS*W floats = 256 KB
  float* part2 = part1 + (size_t)B_ * CHUNKS_ * W_;

  k_rowscan <<<dim3(H_, B_),            256, 0, stream>>>(x, P1, P2);
  k_colpart <<<dim3(W_/256, CHUNKS_, B_), 256, 0, stream>>>(P1, P2, part1, part2);
  k_chunkscan<<<dim3((B_ * W_) / 256),  256, 0, stream>>>(part1, part2);
  k_colscan <<<dim3(W_/256, CHUNKS_, B_), 256, 0, stream>>>(P1, P2, part1, part2);
  k_out     <<<dim3(H_, B_),            256, 0, stream>>>(P1, P2, kk, RR, out);
}

// Round 2
// 262.542 us; speedup vs baseline: 1.9121x; 1.9121x over previous
//
#include <hip/hip_runtime.h>
#include <cstddef>

#define B_ 8
#define H_ 1024
#define W_ 1024
#define NW_ 5
#define CHUNKS_ 8
#define CHROWS_ (H_ / CHUNKS_)   // 128

// ---------------------------------------------------------------------------
// K1: per-row inclusive prefix sums of centered values:
//   P1 = prefix(x - 0.5), P2 = prefix(x^2 - 1/3)
// Centering keeps SAT magnitudes ~1e3 (random walk) instead of ~5e5 — verified
// R1: absmax 3.9e-3 vs threshold 1.3e-2.
// ---------------------------------------------------------------------------
__global__ __launch_bounds__(256) void k_rowscan(const float* __restrict__ x,
                                                 float* __restrict__ P1,
                                                 float* __restrict__ P2) {
  const int y = blockIdx.x, b = blockIdx.y, tid = threadIdx.x;
  const size_t rowoff = ((size_t)b * H_ + y) * W_;
  const float4 v = reinterpret_cast<const float4*>(x + rowoff)[tid];

  float c1[4], c2[4];
  c1[0] = v.x - 0.5f; c1[1] = v.y - 0.5f; c1[2] = v.z - 0.5f; c1[3] = v.w - 0.5f;
  c2[0] = v.x * v.x - (1.0f / 3.0f);
  c2[1] = v.y * v.y - (1.0f / 3.0f);
  c2[2] = v.z * v.z - (1.0f / 3.0f);
  c2[3] = v.w * v.w - (1.0f / 3.0f);

  float i1[4], i2[4];
  i1[0] = c1[0]; i2[0] = c2[0];
  #pragma unroll
  for (int j = 1; j < 4; ++j) { i1[j] = i1[j - 1] + c1[j]; i2[j] = i2[j - 1] + c2[j]; }
  const float s1 = i1[3], s2 = i2[3];

  __shared__ float sh1[256], sh2[256];
  sh1[tid] = s1; sh2[tid] = s2;
  __syncthreads();
  #pragma unroll
  for (int off = 1; off < 256; off <<= 1) {
    float t1 = 0.f, t2 = 0.f;
    if (tid >= off) { t1 = sh1[tid - off]; t2 = sh2[tid - off]; }
    __syncthreads();
    sh1[tid] += t1; sh2[tid] += t2;
    __syncthreads();
  }
  const float e1 = sh1[tid] - s1;
  const float e2 = sh2[tid] - s2;

  float4 o1, o2;
  o1.x = e1 + i1[0]; o1.y = e1 + i1[1]; o1.z = e1 + i1[2]; o1.w = e1 + i1[3];
  o2.x = e2 + i2[0]; o2.y = e2 + i2[1]; o2.z = e2 + i2[2]; o2.w = e2 + i2[3];
  reinterpret_cast<float4*>(P1 + rowoff)[tid] = o1;
  reinterpret_cast<float4*>(P2 + rowoff)[tid] = o2;
}

// ---------------------------------------------------------------------------
// K2a: per-(batch, chunk, column) sums over CHROWS_ rows of P1/P2
// ---------------------------------------------------------------------------
__global__ __launch_bounds__(256) void k_colpart(const float* __restrict__ P1,
                                                 const float* __restrict__ P2,
                                                 float* __restrict__ part1,
                                                 float* __restrict__ part2) {
  const int x = blockIdx.x * 256 + threadIdx.x;
  const int ch = blockIdx.y, b = blockIdx.z;
  const float* p1 = P1 + ((size_t)b * H_ + (size_t)ch * CHROWS_) * W_ + x;
  const float* p2 = P2 + ((size_t)b * H_ + (size_t)ch * CHROWS_) * W_ + x;
  float s1 = 0.f, s2 = 0.f;
  #pragma unroll 8
  for (int i = 0; i < CHROWS_; ++i) {
    s1 += p1[(size_t)i * W_];
    s2 += p2[(size_t)i * W_];
  }
  const size_t o = ((size_t)(b * CHUNKS_ + ch)) * W_ + x;
  part1[o] = s1; part2[o] = s2;
}

// ---------------------------------------------------------------------------
// K2b: in-place exclusive scan of the CHUNKS_ chunk sums per (b, x)
// ---------------------------------------------------------------------------
__global__ __launch_bounds__(256) void k_chunkscan(float* __restrict__ part1,
                                                   float* __restrict__ part2) {
  const int idx = blockIdx.x * 256 + threadIdx.x;
  const int b = idx / W_, x = idx - b * W_;
  float r1 = 0.f, r2 = 0.f;
  #pragma unroll
  for (int ch = 0; ch < CHUNKS_; ++ch) {
    const size_t o = ((size_t)(b * CHUNKS_ + ch)) * W_ + x;
    const float v1 = part1[o], v2 = part2[o];
    part1[o] = r1; part2[o] = r2;
    r1 += v1; r2 += v2;
  }
}

// ---------------------------------------------------------------------------
// K2c: finish the column scan in place: P becomes the full 2-D SAT.
// ---------------------------------------------------------------------------
__global__ __launch_bounds__(256) void k_colscan(float* __restrict__ P1,
                                                 float* __restrict__ P2,
                                                 const float* __restrict__ part1,
                                                 const float* __restrict__ part2) {
  const int x = blockIdx.x * 256 + threadIdx.x;
  const int ch = blockIdx.y, b = blockIdx.z;
  const size_t po = ((size_t)(b * CHUNKS_ + ch)) * W_ + x;
  float r1 = part1[po], r2 = part2[po];
  float* p1 = P1 + ((size_t)b * H_ + (size_t)ch * CHROWS_) * W_ + x;
  float* p2 = P2 + ((size_t)b * H_ + (size_t)ch * CHROWS_) * W_ + x;
  #pragma unroll 4
  for (int i = 0; i < CHROWS_; ++i) {
    const size_t o = (size_t)i * W_;
    r1 += p1[o]; p1[o] = r1;
    r2 += p2[o]; p2[o] = r2;
  }
}

// ---------------------------------------------------------------------------
// K3 v2: per-row vertical-difference strips in LDS.
//   D_w[x] = SAT[yB_w][x] - SAT[yT_w][x]  (per moment) -> box = D[xR]-D[xL].
// Phase 1: 20 coalesced float4 row loads -> ds_write_b128 (10 planes, 40 KB).
// Phase 2: thread t computes pixels {t, t+256, t+512, t+768}: stride-1 lane
// pattern on LDS reads (2 lanes/bank = free per m136), 80 ds_read_b32/thread.
// XCD swizzle: blockIdx%8 == XCD (heuristic) owns a contiguous 128-row
// y-slab per batch -> slab working set ~2 MB fits the 4 MB per-XCD L2.
// ---------------------------------------------------------------------------
__global__ __launch_bounds__(256) void k_out(const float* __restrict__ S1,
                                             const float* __restrict__ S2,
                                             const float* __restrict__ kk,
                                             const float* __restrict__ RR,
                                             float* __restrict__ out) {
  const int i = blockIdx.x;
  const int xcd = i & 7;
  const int s = i >> 3;
  const int b = s >> 7;           // s / 128
  const int y = xcd * 128 + (s & 127);
  const int t = threadIdx.x;

  __shared__ float lds[2 * NW_ * W_];  // plane (2w+m): D for window w, moment m

  const float* base1 = S1 + (size_t)b * H_ * W_;
  const float* base2 = S2 + (size_t)b * H_ * W_;
  const int rad[NW_] = {3, 7, 15, 31, 63};

  #pragma unroll
  for (int w = 0; w < NW_; ++w) {
    const int r = rad[w];
    const int yB = min(y + r, H_ - 1);
    const int yT = y - r - 1;
    const float4 fb1 = reinterpret_cast<const float4*>(base1 + (size_t)yB * W_)[t];
    const float4 fb2 = reinterpret_cast<const float4*>(base2 + (size_t)yB * W_)[t];
    float4 ft1 = {0.f, 0.f, 0.f, 0.f}, ft2 = {0.f, 0.f, 0.f, 0.f};
    if (yT >= 0) {   // block-uniform branch
      ft1 = reinterpret_cast<const float4*>(base1 + (size_t)yT * W_)[t];
      ft2 = reinterpret_cast<const float4*>(base2 + (size_t)yT * W_)[t];
    }
    float4 d1, d2;
    d1.x = fb1.x - ft1.x; d1.y = fb1.y - ft1.y; d1.z = fb1.z - ft1.z; d1.w = fb1.w - ft1.w;
    d2.x = fb2.x - ft2.x; d2.y = fb2.y - ft2.y; d2.z = fb2.z - ft2.z; d2.w = fb2.w - ft2.w;
    reinterpret_cast<float4*>(lds + (size_t)(2 * w) * W_)[t] = d1;
    reinterpret_cast<float4*>(lds + (size_t)(2 * w + 1) * W_)[t] = d2;
  }
  __syncthreads();

  #pragma unroll
  for (int w = 0; w < NW_; ++w) {
    const int r = rad[w];
    const float kw = kk[w];
    const float invR = __builtin_amdgcn_rcpf(RR[w]);
    const int yB = min(y + r, H_ - 1);
    const float rows = (float)(yB - max(y - r, 0) + 1);
    const float* D1 = lds + (size_t)(2 * w) * W_;
    const float* D2 = lds + (size_t)(2 * w + 1) * W_;
    float* orow = out + (((size_t)(b * NW_ + w)) * H_ + y) * W_;
    #pragma unroll
    for (int kp = 0; kp < 4; ++kp) {
      const int xx = t + kp * 256;
      const int xR = min(xx + r, W_ - 1);
      const int xL = xx - r - 1;
      float s1 = D1[xR];
      float s2 = D2[xR];
      if (xL >= 0) { s1 -= D1[xL]; s2 -= D2[xL]; }
      const float cols = (float)(xR - max(xx - r, 0) + 1);
      const float inv = __builtin_amdgcn_rcpf(rows * cols);
      const float Ex  = s1 * inv + 0.5f;
      const float Ex2 = s2 * inv + (1.0f / 3.0f);
      const float var = Ex2 - Ex * Ex;
      const float dev = __builtin_amdgcn_sqrtf(fmaxf(var, 1e-6f));
      orow[xx] = Ex * (1.0f + kw * (dev * invR - 1.0f));
    }
  }
}

// ---------------------------------------------------------------------------
extern "C" void kernel_launch(void* const* d_in, const int* in_sizes, int n_in,
                              void* d_out, int out_size, void* d_ws, size_t ws_size,
                              hipStream_t stream) {
  const float* x  = (const float*)d_in[0];
  const float* kk = (const float*)d_in[1];
  const float* RR = (const float*)d_in[2];
  float* out = (float*)d_out;

  const size_t plane = (size_t)B_ * H_ * W_;
  float* P1 = (float*)d_ws;
  float* P2 = P1 + plane;
  float* part1 = P2 + plane;
  float* part2 = part1 + (size_t)B_ * CHUNKS_ * W_;

  k_rowscan <<<dim3(H_, B_),              256, 0, stream>>>(x, P1, P2);
  k_colpart <<<dim3(W_/256, CHUNKS_, B_), 256, 0, stream>>>(P1, P2, part1, part2);
  k_chunkscan<<<dim3((B_ * W_) / 256),    256, 0, stream>>>(part1, part2);
  k_colscan <<<dim3(W_/256, CHUNKS_, B_), 256, 0, stream>>>(P1, P2, part1, part2);
  k_out     <<<dim3(B_ * H_),             256, 0, stream>>>(P1, P2, kk, RR, out);
}

// Round 3
// 251.656 us; speedup vs baseline: 1.9948x; 1.0433x over previous
//
#include <hip/hip_runtime.h>
#include <cstddef>

#define B_ 8
#define H_ 1024
#define W_ 1024
#define NW_ 5
#define CHUNKS_ 32
#define CHROWS_ (H_ / CHUNKS_)   // 32

// ---------------------------------------------------------------------------
// K1: fused row-prefix + column chunk sums.
// One block per (chunk, b): 4 waves x 8 rows each. A wave scans a full
// 1024-px row: 4 float4 groups, local prefix-of-4, 6-round __shfl_up lane
// scan, carry between groups — NO __syncthreads in the row loop (old
// Hillis-Steele paid 16 barriers/row). Centered values (x-0.5, x^2-1/3)
// keep SAT magnitude ~1e3 (verified R1: absmax 3.9e-3 vs thr 1.3e-2).
// Each wave also accumulates per-column sums of its 8 rows in registers
// (8 float4/moment); one LDS round-trip at the end reduces the 4 waves
// into the chunk-sum row part[b][ch][x]. Kills colpart's 64 MB re-read.
// ---------------------------------------------------------------------------
__global__ __launch_bounds__(256) void k_rowpart(const float* __restrict__ x,
                                                 float* __restrict__ P1,
                                                 float* __restrict__ P2,
                                                 float* __restrict__ part1,
                                                 float* __restrict__ part2) {
  const int ch = blockIdx.x, b = blockIdx.y;
  const int wave = threadIdx.x >> 6, lane = threadIdx.x & 63;
  const int row0 = ch * CHROWS_ + wave * (CHROWS_ / 4);  // 8 rows per wave

  float4 acc1[4], acc2[4];
  #pragma unroll
  for (int c = 0; c < 4; ++c) {
    acc1[c] = make_float4(0.f, 0.f, 0.f, 0.f);
    acc2[c] = make_float4(0.f, 0.f, 0.f, 0.f);
  }

  for (int rr = 0; rr < CHROWS_ / 4; ++rr) {
    const int y = row0 + rr;
    const size_t rowoff = ((size_t)b * H_ + y) * W_;
    float carry1 = 0.f, carry2 = 0.f;
    #pragma unroll
    for (int c = 0; c < 4; ++c) {
      const float4 v = reinterpret_cast<const float4*>(x + rowoff + c * 256)[lane];
      float l1[4], l2[4];
      l1[0] = v.x - 0.5f;
      l1[1] = l1[0] + (v.y - 0.5f);
      l1[2] = l1[1] + (v.z - 0.5f);
      l1[3] = l1[2] + (v.w - 0.5f);
      l2[0] = v.x * v.x - (1.0f / 3.0f);
      l2[1] = l2[0] + (v.y * v.y - (1.0f / 3.0f));
      l2[2] = l2[1] + (v.z * v.z - (1.0f / 3.0f));
      l2[3] = l2[2] + (v.w * v.w - (1.0f / 3.0f));
      const float s1 = l1[3], s2 = l2[3];
      float inc1 = s1, inc2 = s2;
      #pragma unroll
      for (int off = 1; off < 64; off <<= 1) {
        const float t1 = __shfl_up(inc1, off);
        const float t2 = __shfl_up(inc2, off);
        if (lane >= off) { inc1 += t1; inc2 += t2; }
      }
      const float base1 = carry1 + inc1 - s1;
      const float base2 = carry2 + inc2 - s2;
      float4 o1, o2;
      o1.x = base1 + l1[0]; o1.y = base1 + l1[1]; o1.z = base1 + l1[2]; o1.w = base1 + l1[3];
      o2.x = base2 + l2[0]; o2.y = base2 + l2[1]; o2.z = base2 + l2[2]; o2.w = base2 + l2[3];
      reinterpret_cast<float4*>(P1 + rowoff + c * 256)[lane] = o1;
      reinterpret_cast<float4*>(P2 + rowoff + c * 256)[lane] = o2;
      acc1[c].x += o1.x; acc1[c].y += o1.y; acc1[c].z += o1.z; acc1[c].w += o1.w;
      acc2[c].x += o2.x; acc2[c].y += o2.y; acc2[c].z += o2.z; acc2[c].w += o2.w;
      carry1 += __shfl(inc1, 63);
      carry2 += __shfl(inc2, 63);
    }
  }

  // cross-wave reduction of column sums -> part[b][ch][:]
  __shared__ float red[4][2][W_];  // 32 KB
  #pragma unroll
  for (int c = 0; c < 4; ++c) {
    reinterpret_cast<float4*>(&red[wave][0][c * 256])[lane] = acc1[c];
    reinterpret_cast<float4*>(&red[wave][1][c * 256])[lane] = acc2[c];
  }
  __syncthreads();
  const int t = threadIdx.x;  // thread t reduces cols 4t..4t+3
  float4 r1 = make_float4(0.f, 0.f, 0.f, 0.f), r2 = r1;
  #pragma unroll
  for (int w = 0; w < 4; ++w) {
    const float4 a = reinterpret_cast<const float4*>(&red[w][0][0])[t];
    const float4 c2 = reinterpret_cast<const float4*>(&red[w][1][0])[t];
    r1.x += a.x; r1.y += a.y; r1.z += a.z; r1.w += a.w;
    r2.x += c2.x; r2.y += c2.y; r2.z += c2.z; r2.w += c2.w;
  }
  const size_t po = ((size_t)(b * CHUNKS_ + ch)) * W_;
  reinterpret_cast<float4*>(part1 + po)[t] = r1;
  reinterpret_cast<float4*>(part2 + po)[t] = r2;
}

// ---------------------------------------------------------------------------
// K2: column rescan, absorbing the chunk-offset scan. Each block (b, ch,
// 256-col strip) sums the (<32, L2-resident) part rows below it for its
// exclusive offset, then rescans its 32 rows in place -> full 2-D SAT.
// 1024 blocks (16 waves/CU) and a 32-long serial chain (was 128).
// ---------------------------------------------------------------------------
__global__ __launch_bounds__(256) void k_colscan(float* __restrict__ P1,
                                                 float* __restrict__ P2,
                                                 const float* __restrict__ part1,
                                                 const float* __restrict__ part2) {
  const int xx = blockIdx.x * 256 + threadIdx.x;
  const int ch = blockIdx.y, b = blockIdx.z;
  float r1 = 0.f, r2 = 0.f;
  for (int c = 0; c < ch; ++c) {   // block-uniform trip count
    const size_t o = ((size_t)(b * CHUNKS_ + c)) * W_ + xx;
    r1 += part1[o];
    r2 += part2[o];
  }
  float* p1 = P1 + ((size_t)b * H_ + (size_t)ch * CHROWS_) * W_ + xx;
  float* p2 = P2 + ((size_t)b * H_ + (size_t)ch * CHROWS_) * W_ + xx;
  #pragma unroll 8
  for (int i = 0; i < CHROWS_; ++i) {
    const size_t o = (size_t)i * W_;
    r1 += p1[o]; p1[o] = r1;
    r2 += p2[o]; p2[o] = r2;
  }
}

// ---------------------------------------------------------------------------
// K3: per-row vertical-difference strips in LDS (R2 version, unchanged —
// took k_out 300 -> ~65 us). D_w[x] = SAT[yB][x]-SAT[yT][x]; box = D[xR]-D[xL].
// ---------------------------------------------------------------------------
__global__ __launch_bounds__(256) void k_out(const float* __restrict__ S1,
                                             const float* __restrict__ S2,
                                             const float* __restrict__ kk,
                                             const float* __restrict__ RR,
                                             float* __restrict__ out) {
  const int i = blockIdx.x;
  const int xcd = i & 7;
  const int s = i >> 3;
  const int b = s >> 7;
  const int y = xcd * 128 + (s & 127);
  const int t = threadIdx.x;

  __shared__ float lds[2 * NW_ * W_];  // 40 KB

  const float* base1 = S1 + (size_t)b * H_ * W_;
  const float* base2 = S2 + (size_t)b * H_ * W_;
  const int rad[NW_] = {3, 7, 15, 31, 63};

  #pragma unroll
  for (int w = 0; w < NW_; ++w) {
    const int r = rad[w];
    const int yB = min(y + r, H_ - 1);
    const int yT = y - r - 1;
    const float4 fb1 = reinterpret_cast<const float4*>(base1 + (size_t)yB * W_)[t];
    const float4 fb2 = reinterpret_cast<const float4*>(base2 + (size_t)yB * W_)[t];
    float4 ft1 = {0.f, 0.f, 0.f, 0.f}, ft2 = {0.f, 0.f, 0.f, 0.f};
    if (yT >= 0) {   // block-uniform branch
      ft1 = reinterpret_cast<const float4*>(base1 + (size_t)yT * W_)[t];
      ft2 = reinterpret_cast<const float4*>(base2 + (size_t)yT * W_)[t];
    }
    float4 d1, d2;
    d1.x = fb1.x - ft1.x; d1.y = fb1.y - ft1.y; d1.z = fb1.z - ft1.z; d1.w = fb1.w - ft1.w;
    d2.x = fb2.x - ft2.x; d2.y = fb2.y - ft2.y; d2.z = fb2.z - ft2.z; d2.w = fb2.w - ft2.w;
    reinterpret_cast<float4*>(lds + (size_t)(2 * w) * W_)[t] = d1;
    reinterpret_cast<float4*>(lds + (size_t)(2 * w + 1) * W_)[t] = d2;
  }
  __syncthreads();

  #pragma unroll
  for (int w = 0; w < NW_; ++w) {
    const int r = rad[w];
    const float kw = kk[w];
    const float invR = __builtin_amdgcn_rcpf(RR[w]);
    const int yB = min(y + r, H_ - 1);
    const float rows = (float)(yB - max(y - r, 0) + 1);
    const float* D1 = lds + (size_t)(2 * w) * W_;
    const float* D2 = lds + (size_t)(2 * w + 1) * W_;
    float* orow = out + (((size_t)(b * NW_ + w)) * H_ + y) * W_;
    #pragma unroll
    for (int kp = 0; kp < 4; ++kp) {
      const int xx = t + kp * 256;
      const int xR = min(xx + r, W_ - 1);
      const int xL = xx - r - 1;
      float s1 = D1[xR];
      float s2 = D2[xR];
      if (xL >= 0) { s1 -= D1[xL]; s2 -= D2[xL]; }
      const float cols = (float)(xR - max(xx - r, 0) + 1);
      const float inv = __builtin_amdgcn_rcpf(rows * cols);
      const float Ex  = s1 * inv + 0.5f;
      const float Ex2 = s2 * inv + (1.0f / 3.0f);
      const float var = Ex2 - Ex * Ex;
      const float dev = __builtin_amdgcn_sqrtf(fmaxf(var, 1e-6f));
      orow[xx] = Ex * (1.0f + kw * (dev * invR - 1.0f));
    }
  }
}

// ---------------------------------------------------------------------------
extern "C" void kernel_launch(void* const* d_in, const int* in_sizes, int n_in,
                              void* d_out, int out_size, void* d_ws, size_t ws_size,
                              hipStream_t stream) {
  const float* x  = (const float*)d_in[0];
  const float* kk = (const float*)d_in[1];
  const float* RR = (const float*)d_in[2];
  float* out = (float*)d_out;

  const size_t plane = (size_t)B_ * H_ * W_;            // 32 MB per moment
  float* P1 = (float*)d_ws;
  float* P2 = P1 + plane;
  float* part1 = P2 + plane;                            // 1 MB each
  float* part2 = part1 + (size_t)B_ * CHUNKS_ * W_;

  k_rowpart <<<dim3(CHUNKS_, B_),          256, 0, stream>>>(x, P1, P2, part1, part2);
  k_colscan <<<dim3(W_/256, CHUNKS_, B_),  256, 0, stream>>>(P1, P2, part1, part2);
  k_out     <<<dim3(B_ * H_),              256, 0, stream>>>(P1, P2, kk, RR, out);
}